// Round 7
// baseline (306.675 us; speedup 1.0000x reference)
//
#include <hip/hip_runtime.h>
#include <hip/hip_bf16.h>

#define BB 64
#define TT 1024
#define AA 128
#define DQ 1024
#define DV 512

typedef __bf16 bf16x8_t __attribute__((ext_vector_type(8)));
typedef __bf16 bf16x4_t __attribute__((ext_vector_type(4)));
typedef float f32x4_t __attribute__((ext_vector_type(4)));

__device__ __forceinline__ float ftanh(float x) {
    float e = __expf(2.0f * x);
    return 1.0f - 2.0f / (e + 1.0f);
}
__device__ __forceinline__ __bf16 bhi(float x) { return (__bf16)x; }
__device__ __forceinline__ __bf16 blo(float x) {
    __bf16 h = (__bf16)x;
    return (__bf16)(x - (float)h);
}

// ================= K_pre: fused prep + query + zconv-MFMA =================
// blocks 0..15   : pwm pack  (Wm -> frag-ordered bf16 hi/lo)
// blocks 16..23  : pwc pack  (Wconv^T -> frag-ordered, kc padded to 64)
// blocks 24..279 : query GEMM (4 a-groups x 64 b)
// blocks 280..343: zq (z = X @ Wloc per b, MFMA, Wloc staged via LDS) -> pz packed
__global__ __launch_bounds__(256) void k_pre(
    const float* __restrict__ Wm, const float* __restrict__ Wconv,
    const float* __restrict__ Wloc, const float* __restrict__ query,
    const float* __restrict__ Wq, const float* __restrict__ xcat,
    __bf16* __restrict__ pwmhi, __bf16* __restrict__ pwmlo,
    __bf16* __restrict__ pwchi, __bf16* __restrict__ pwclo,
    __bf16* __restrict__ pzhi, __bf16* __restrict__ pzlo,
    float* __restrict__ q_ws) {
    __shared__ float ls[14784];
    int bx = blockIdx.x, tid = threadIdx.x;
    if (bx < 16) {
        // ---- pwm: Wm[d][a] -> frag order, slab s covers d0..d0+32 ----
        int s = bx, d0 = s * 32;
        for (int i = tid; i < 4096; i += 256) {
            int dd = i >> 7, a = i & 127;
            ls[a * 33 + dd] = Wm[(d0 + dd) * AA + a];
        }
        __syncthreads();
#pragma unroll
        for (int u = 0; u < 2; u++) {
            int pos = tid * 2 + u;  // 0..511
            int l15 = pos & 15, lq = (pos >> 4) & 3, g = pos >> 6;
            bf16x8_t h8, l8;
#pragma unroll
            for (int j = 0; j < 8; j++) {
                float x = ls[(g * 16 + l15) * 33 + lq * 8 + j];
                h8[j] = bhi(x);
                l8[j] = blo(x);
            }
            size_t off = (size_t)(s * 512 + pos) * 8;
            *(bf16x8_t*)(pwmhi + off) = h8;
            *(bf16x8_t*)(pwmlo + off) = l8;
        }
    } else if (bx < 24) {
        // ---- pwc: Wconv[kc][f] -> wct[f][kc] frag order ----
        int f0 = (bx - 16) * 128;
        for (int i = tid; i < 8192; i += 256) {
            int kc = i >> 7, f = i & 127;
            ls[f * 65 + kc] = (kc < 62) ? Wconv[kc * 1024 + f0 + f] : 0.f;
        }
        __syncthreads();
#pragma unroll
        for (int u = 0; u < 4; u++) {
            int pos = tid * 4 + u;  // 0..1023
            int fg = pos >> 7, kq = (pos >> 6) & 1, ln = pos & 63;
            int l15 = ln & 15, lq = ln >> 4;
            bf16x8_t h8, l8;
#pragma unroll
            for (int j = 0; j < 8; j++) {
                float x = ls[(fg * 16 + l15) * 65 + kq * 32 + lq * 8 + j];
                h8[j] = bhi(x);
                l8[j] = blo(x);
            }
            size_t off = ((size_t)(((bx - 16) * 8 + fg) * 2 + kq) * 64 + ln) * 8;
            *(bf16x8_t*)(pwchi + off) = h8;
            *(bf16x8_t*)(pwclo + off) = l8;
        }
    } else if (bx < 280) {
        // ---- query: q[b,a] = tanh(sum_d query[b,d]*Wq[d,a]) ----
        int bidx = bx - 24;
        int b = bidx >> 2, ag = bidx & 3;
        int lane32 = tid & 31, grp = tid >> 5;  // 8 d-groups of 128
        int a = ag * 32 + lane32;
        float acc = 0.f;
        const float* qrow = query + b * DQ + grp * 128;
        const float* wqb = Wq + (size_t)grp * 128 * AA + a;
        for (int d = 0; d < 128; d += 4) {
            float4 q4 = *(const float4*)(qrow + d);
            acc += q4.x * wqb[d * AA] + q4.y * wqb[(d + 1) * AA] +
                   q4.z * wqb[(d + 2) * AA] + q4.w * wqb[(d + 3) * AA];
        }
        ls[grp * 33 + lane32] = acc;
        __syncthreads();
        if (tid < 32) {
            float s = 0.f;
#pragma unroll
            for (int j = 0; j < 8; j++) s += ls[j * 33 + tid];
            q_ws[b * AA + ag * 32 + tid] = ftanh(s);
        }
    } else {
        // ---- zq: z[kc][a] = sum_t X[kc][t]*Wloc[t][a], X from shifted xcat ----
        int b = bx - 280;
        float* xs0 = ls;          // 1056
        float* xs1 = ls + 1056;   // 1056
        float* wl = ls + 2112;    // 32*132
        float* zs = ls + 6336;    // 64*132
        for (int i = tid; i < 1056; i += 256) {
            int t = i - 16;
            float2 xv = (t >= 0 && t < TT) ? *(const float2*)(xcat + (size_t)(b * TT + t) * 2)
                                           : make_float2(0.f, 0.f);
            xs0[i] = xv.x;
            xs1[i] = xv.y;
        }
        int lane = tid & 63, wid = tid >> 6;
        int wm = wid >> 1, wn = wid & 1;
        int l15 = lane & 15, lq = lane >> 4;
        f32x4_t zacc[2][4];
#pragma unroll
        for (int mi = 0; mi < 2; mi++)
#pragma unroll
            for (int ni = 0; ni < 4; ni++) zacc[mi][ni] = (f32x4_t){0.f, 0.f, 0.f, 0.f};
        for (int s = 0; s < 32; s++) {
            int t0 = s * 32;
            __syncthreads();  // protect wl (prev reads) / xs initial load
#pragma unroll
            for (int k2 = 0; k2 < 4; k2++) {
                int slot = tid + k2 * 256;      // 1024 float4 slots
                int tt = slot >> 5, c4 = slot & 31;
                *(float4*)(wl + tt * 132 + c4 * 4) =
                    *(const float4*)(Wloc + (size_t)(t0 + tt) * AA + c4 * 4);
            }
            __syncthreads();
            bf16x8_t ah[2], al[2];
#pragma unroll
            for (int mi = 0; mi < 2; mi++) {
                int kc = wm * 32 + mi * 16 + l15;
                const float* xsc = (kc & 1) ? xs1 : xs0;
                int base = t0 + lq * 8 + (kc >> 1) + 1;
#pragma unroll
                for (int j = 0; j < 8; j++) {
                    float x = xsc[base + j];
                    ah[mi][j] = bhi(x);
                    al[mi][j] = blo(x);
                }
            }
#pragma unroll
            for (int ni = 0; ni < 4; ni++) {
                int a = wn * 64 + ni * 16 + l15;
                bf16x8_t bh, bl;
#pragma unroll
                for (int j = 0; j < 8; j++) {
                    float x = wl[(lq * 8 + j) * 132 + a];
                    bh[j] = bhi(x);
                    bl[j] = blo(x);
                }
#pragma unroll
                for (int mi = 0; mi < 2; mi++) {
                    zacc[mi][ni] = __builtin_amdgcn_mfma_f32_16x16x32_bf16(ah[mi], bh, zacc[mi][ni], 0, 0, 0);
                    zacc[mi][ni] = __builtin_amdgcn_mfma_f32_16x16x32_bf16(al[mi], bh, zacc[mi][ni], 0, 0, 0);
                    zacc[mi][ni] = __builtin_amdgcn_mfma_f32_16x16x32_bf16(ah[mi], bl, zacc[mi][ni], 0, 0, 0);
                }
            }
        }
        __syncthreads();
#pragma unroll
        for (int mi = 0; mi < 2; mi++)
#pragma unroll
            for (int ni = 0; ni < 4; ni++)
#pragma unroll
                for (int r = 0; r < 4; r++)
                    zs[(wm * 32 + mi * 16 + lq * 4 + r) * 132 + wn * 64 + ni * 16 + l15] = zacc[mi][ni][r];
        __syncthreads();
#pragma unroll
        for (int u = 0; u < 4; u++) {
            int pos = tid * 4 + u;  // 0..1023
            int a16 = pos >> 7, kq = (pos >> 6) & 1, ln = pos & 63;
            int pl15 = ln & 15, plq = ln >> 4;
            bf16x8_t h8, l8;
#pragma unroll
            for (int j = 0; j < 8; j++) {
                float x = zs[(kq * 32 + plq * 8 + j) * 132 + a16 * 16 + pl15];
                h8[j] = bhi(x);
                l8[j] = blo(x);
            }
            size_t off = (((size_t)b * 16 + a16 * 2 + kq) * 64 + ln) * 8;
            *(bf16x8_t*)(pzhi + off) = h8;
            *(bf16x8_t*)(pzlo + off) = l8;
        }
    }
}

// ================= K_main: v = tanh(value@Wm), loc = tanh(wct@z), score =================
// 64 t-rows x 128 a; 1024 blocks; 4 waves (2x2), wave = 32x64.
// Double-buffered LDS, ONE barrier per K-iter, depth-2 reg prefetch, all frag loads coalesced.
__global__ __launch_bounds__(256) void k_main(
    const float* __restrict__ value,
    const __bf16* __restrict__ pwmhi, const __bf16* __restrict__ pwmlo,
    const __bf16* __restrict__ pwchi, const __bf16* __restrict__ pwclo,
    const __bf16* __restrict__ pzhi, const __bf16* __restrict__ pzlo,
    const float* __restrict__ q_ws, const float* __restrict__ Wv,
    _Float16* __restrict__ v_ws, float* __restrict__ score) {
    int b = blockIdx.x >> 4;
    int trow0 = (blockIdx.x & 15) << 6;
    int tid = threadIdx.x;
    int lane = tid & 63, wid = tid >> 6;
    int wm = wid >> 1, wn = wid & 1;
    int l15 = lane & 15, lq = lane >> 4;

    __shared__ __bf16 as_hi[2][64 * 40];
    __shared__ __bf16 as_lo[2][64 * 40];
    __shared__ float sc_red[128];

    f32x4_t acc[2][4];
#pragma unroll
    for (int mi = 0; mi < 2; mi++)
#pragma unroll
        for (int ni = 0; ni < 4; ni++) acc[mi][ni] = (f32x4_t){0.f, 0.f, 0.f, 0.f};

    const float* vbase = value + (size_t)(b * TT + trow0) * DV;
    int row0 = tid >> 3, c4 = tid & 7;      // slot l: row = row0 + (l?32:0)? no: slot=tid+l*256
    // slot decomposition: slot = tid + l*256 -> row = slot>>3 in 0..63, col4 = slot&7
    float4 cur0[2], cur1[2];
#pragma unroll
    for (int l = 0; l < 2; l++) {
        int slot = tid + l * 256;
        cur0[l] = *(const float4*)(vbase + (size_t)(slot >> 3) * DV + 0 + (slot & 7) * 4);
    }
#pragma unroll
    for (int l = 0; l < 2; l++) {
        int slot = tid + l * 256;
        cur1[l] = *(const float4*)(vbase + (size_t)(slot >> 3) * DV + 32 + (slot & 7) * 4);
    }
    // prolog: tile0 -> buf0
#pragma unroll
    for (int l = 0; l < 2; l++) {
        int slot = tid + l * 256;
        int t = slot >> 3, cc = slot & 7;
        float4 v4 = cur0[l];
        bf16x4_t hv, lv;
        hv[0] = bhi(v4.x); lv[0] = blo(v4.x);
        hv[1] = bhi(v4.y); lv[1] = blo(v4.y);
        hv[2] = bhi(v4.z); lv[2] = blo(v4.z);
        hv[3] = bhi(v4.w); lv[3] = blo(v4.w);
        *(bf16x4_t*)(&as_hi[0][t * 40 + cc * 4]) = hv;
        *(bf16x4_t*)(&as_lo[0][t * 40 + cc * 4]) = lv;
    }

    for (int it = 0; it < 16; ++it) {
        __syncthreads();  // separates prev-iter reads of buf[(it+1)&1] from this iter's writes
        // B frags (L2-hot, coalesced), consumed at loop bottom
        bf16x8_t bh[4], bl[4];
#pragma unroll
        for (int ni = 0; ni < 4; ni++) {
            size_t poff = (size_t)((it * 8 + wn * 4 + ni) * 64 + lane) * 8;
            bh[ni] = *(const bf16x8_t*)(pwmhi + poff);
            bl[ni] = *(const bf16x8_t*)(pwmlo + poff);
        }
        int nb = (it + 1) & 1;
        if (it < 15) {
            // convert tile it+1 (loaded 1-2 iters ago) into the other buffer
#pragma unroll
            for (int l = 0; l < 2; l++) {
                int slot = tid + l * 256;
                int t = slot >> 3, cc = slot & 7;
                float4 v4 = nb ? cur1[l] : cur0[l];
                bf16x4_t hv, lv;
                hv[0] = bhi(v4.x); lv[0] = blo(v4.x);
                hv[1] = bhi(v4.y); lv[1] = blo(v4.y);
                hv[2] = bhi(v4.z); lv[2] = blo(v4.z);
                hv[3] = bhi(v4.w); lv[3] = blo(v4.w);
                *(bf16x4_t*)(&as_hi[nb][t * 40 + cc * 4]) = hv;
                *(bf16x4_t*)(&as_lo[nb][t * 40 + cc * 4]) = lv;
            }
        }
        if (it < 14) {
            // prefetch tile it+2 into the register set just freed (parity it&1)
#pragma unroll
            for (int l = 0; l < 2; l++) {
                int slot = tid + l * 256;
                float4 v4 = *(const float4*)(vbase + (size_t)(slot >> 3) * DV + (it + 2) * 32 + (slot & 7) * 4);
                if (it & 1) cur1[l] = v4; else cur0[l] = v4;
            }
        }
        int cb = it & 1;
        bf16x8_t ah[2], al[2];
#pragma unroll
        for (int mi = 0; mi < 2; mi++) {
            int off2 = (wm * 32 + mi * 16 + l15) * 40 + lq * 8;
            ah[mi] = *(const bf16x8_t*)(&as_hi[cb][off2]);
            al[mi] = *(const bf16x8_t*)(&as_lo[cb][off2]);
        }
#pragma unroll
        for (int ni = 0; ni < 4; ni++)
#pragma unroll
            for (int mi = 0; mi < 2; mi++) {
                acc[mi][ni] = __builtin_amdgcn_mfma_f32_16x16x32_bf16(ah[mi], bh[ni], acc[mi][ni], 0, 0, 0);
                acc[mi][ni] = __builtin_amdgcn_mfma_f32_16x16x32_bf16(al[mi], bh[ni], acc[mi][ni], 0, 0, 0);
                acc[mi][ni] = __builtin_amdgcn_mfma_f32_16x16x32_bf16(ah[mi], bl[ni], acc[mi][ni], 0, 0, 0);
            }
    }

    // ---- loc gemm: K=64 over packed pwc (A) and pz (B), all coalesced ----
    f32x4_t lacc[2][4];
#pragma unroll
    for (int mi = 0; mi < 2; mi++)
#pragma unroll
        for (int ni = 0; ni < 4; ni++) lacc[mi][ni] = (f32x4_t){0.f, 0.f, 0.f, 0.f};
#pragma unroll
    for (int kq = 0; kq < 2; kq++) {
        bf16x8_t a2h[2], a2l[2], b2h[4], b2l[4];
#pragma unroll
        for (int mi = 0; mi < 2; mi++) {
            int fg = (trow0 >> 4) + wm * 2 + mi;
            size_t off = ((size_t)(fg * 2 + kq) * 64 + lane) * 8;
            a2h[mi] = *(const bf16x8_t*)(pwchi + off);
            a2l[mi] = *(const bf16x8_t*)(pwclo + off);
        }
#pragma unroll
        for (int ni = 0; ni < 4; ni++) {
            size_t off = (((size_t)b * 16 + (wn * 4 + ni) * 2 + kq) * 64 + lane) * 8;
            b2h[ni] = *(const bf16x8_t*)(pzhi + off);
            b2l[ni] = *(const bf16x8_t*)(pzlo + off);
        }
#pragma unroll
        for (int mi = 0; mi < 2; mi++)
#pragma unroll
            for (int ni = 0; ni < 4; ni++) {
                lacc[mi][ni] = __builtin_amdgcn_mfma_f32_16x16x32_bf16(a2h[mi], b2h[ni], lacc[mi][ni], 0, 0, 0);
                lacc[mi][ni] = __builtin_amdgcn_mfma_f32_16x16x32_bf16(a2l[mi], b2h[ni], lacc[mi][ni], 0, 0, 0);
                lacc[mi][ni] = __builtin_amdgcn_mfma_f32_16x16x32_bf16(a2h[mi], b2l[ni], lacc[mi][ni], 0, 0, 0);
            }
    }

    // ---- epilogue ----
    float qv[4], wv[4];
#pragma unroll
    for (int ni = 0; ni < 4; ni++) {
        int a = wn * 64 + ni * 16 + l15;
        qv[ni] = q_ws[b * AA + a];
        wv[ni] = Wv[a];
    }
#pragma unroll
    for (int mi = 0; mi < 2; mi++) {
#pragma unroll
        for (int r = 0; r < 4; r++) {
            int tl = wm * 32 + mi * 16 + lq * 4 + r;
            int t = trow0 + tl;
            float s = 0.f;
#pragma unroll
            for (int ni = 0; ni < 4; ni++) {
                float v = ftanh(acc[mi][ni][r]);
                float loc = ftanh(lacc[mi][ni][r]);
                int a = wn * 64 + ni * 16 + l15;
                v_ws[(size_t)(b * TT + t) * AA + a] = (_Float16)v;
                s += ftanh(qv[ni] + v + loc) * wv[ni];
            }
            s += __shfl_xor(s, 1, 64);
            s += __shfl_xor(s, 2, 64);
            s += __shfl_xor(s, 4, 64);
            s += __shfl_xor(s, 8, 64);
            if (l15 == 0) sc_red[wn * 64 + tl] = s;
        }
    }
    __syncthreads();
    if (tid < 64) score[b * TT + trow0 + tid] = sc_red[tid] + sc_red[64 + tid];
}

// ================= K_post: softmax + context fused, no atomics =================
// Grid (2 a/t-halves, 64 b). Each block: full softmax (redundant, 4KB), writes its
// align t-half, computes context for its 64-a half over all t.
__global__ __launch_bounds__(256) void k_post(const float* __restrict__ score,
                                              const _Float16* __restrict__ v_ws,
                                              float* __restrict__ out) {
    int h = blockIdx.x & 1, b = blockIdx.x >> 1;
    int tid = threadIdx.x;
    __shared__ float sc[1024];
    __shared__ float red[4];
    __shared__ float part[4][72];
    float s[4];
#pragma unroll
    for (int i = 0; i < 4; i++) s[i] = score[b * TT + tid + i * 256];
    float m = fmaxf(fmaxf(s[0], s[1]), fmaxf(s[2], s[3]));
    for (int off = 32; off; off >>= 1) m = fmaxf(m, __shfl_xor(m, off, 64));
    int wd = tid >> 6;
    if ((tid & 63) == 0) red[wd] = m;
    __syncthreads();
    float M = fmaxf(fmaxf(red[0], red[1]), fmaxf(red[2], red[3]));
    __syncthreads();
    float sum = 0.f;
#pragma unroll
    for (int i = 0; i < 4; i++) {
        float e = __expf(s[i] - M);
        sc[tid + i * 256] = e;
        sum += e;
    }
    for (int off = 32; off; off >>= 1) sum += __shfl_xor(sum, off, 64);
    if ((tid & 63) == 0) red[wd] = sum;
    __syncthreads();
    float inv = 1.0f / (red[0] + red[1] + red[2] + red[3]);
    // align out: this block's t-half
    float* align_out = out + 8192 + b * TT;
#pragma unroll
    for (int i = 0; i < 2; i++) {
        int t = h * 512 + tid + i * 256;
        align_out[t] = sc[t] * inv;
    }
    // context: this block's 64-a half
    int al = tid & 63, tg = tid >> 6;
    const _Float16* vb = v_ws + (size_t)b * TT * AA + h * 64 + al;
    float a0 = 0.f, a1 = 0.f, a2 = 0.f, a3 = 0.f;
    for (int t = tg * 4; t < TT; t += 16) {
        a0 += sc[t + 0] * (float)vb[(size_t)(t + 0) * AA];
        a1 += sc[t + 1] * (float)vb[(size_t)(t + 1) * AA];
        a2 += sc[t + 2] * (float)vb[(size_t)(t + 2) * AA];
        a3 += sc[t + 3] * (float)vb[(size_t)(t + 3) * AA];
    }
    part[tg][al] = (a0 + a1 + a2 + a3) * inv;
    __syncthreads();
    if (tid < 64)
        out[b * AA + h * 64 + tid] = part[0][tid] + part[1][tid] + part[2][tid] + part[3][tid];
}

extern "C" void kernel_launch(void* const* d_in, const int* in_sizes, int n_in,
                              void* d_out, int out_size, void* d_ws, size_t ws_size,
                              hipStream_t stream) {
    const float* query = (const float*)d_in[0];
    const float* value = (const float*)d_in[1];
    const float* xcat  = (const float*)d_in[2];
    const float* Wq    = (const float*)d_in[3];
    const float* Wm    = (const float*)d_in[4];
    const float* Wv    = (const float*)d_in[5];
    const float* Wconv = (const float*)d_in[6];
    const float* Wloc  = (const float*)d_in[7];
    float* out = (float*)d_out;

    float* ws = (float*)d_ws;
    float* q_ws  = ws;                       // 8192
    float* sc_ws = ws + 8192;                // 65536
    _Float16* v_ws = (_Float16*)(ws + 8192 + 65536);   // 8388608 halfs
    __bf16* pwmhi = (__bf16*)(ws + 8192 + 65536 + 4194304);
    __bf16* pwmlo = pwmhi + 65536;
    __bf16* pwchi = pwmlo + 65536;
    __bf16* pwclo = pwchi + 65536;
    __bf16* pzhi  = pwclo + 65536;           // 524288
    __bf16* pzlo  = pzhi + 524288;

    k_pre<<<344, 256, 0, stream>>>(Wm, Wconv, Wloc, query, Wq, xcat,
                                   pwmhi, pwmlo, pwchi, pwclo, pzhi, pzlo, q_ws);
    k_main<<<1024, 256, 0, stream>>>(value, pwmhi, pwmlo, pwchi, pwclo, pzhi, pzlo,
                                     q_ws, Wv, v_ws, sc_ws);
    k_post<<<128, 256, 0, stream>>>(sc_ws, v_ws, out);
}